// Round 15
// baseline (550.483 us; speedup 1.0000x reference)
//
#include <hip/hip_runtime.h>
#include <hip/hip_fp16.h>

#define NF 21
#define BN 12         // nodes per block in gather kernels (12*21 = 252 lanes used)
#define SCAN_T 1024
#define BSH 9         // bucket shift: 512 nodes per bucket
#define BSZ 512       // nodes per bucket
#define NBB 256       // max buckets (n <= 131072)
#define NBMAX 1024    // bases/cur allocation (layout-compatible)
#define BINR 64       // rounds per bin block (no pl[] -> VGPR-light at any BINR)
#define BINCHUNK (BINR * 256)

#define ATOMIC_ADD_F32(p, v) unsafeAtomicAdd((p), (v))

// Diagnostic: fills output with a recognizable sentinel if ws_size is insufficient.
__global__ __launch_bounds__(64) void sentinel_kernel(float* out, int m) {
    int i = blockIdx.x * 64 + threadIdx.x;
    if (i < m) out[i] = 0.109375f;
}

// --- Bucketed CSR build ------------------------------------------------------
__global__ __launch_bounds__(256) void bucket_count_kernel(
    const int* __restrict__ ei, int* __restrict__ bases, int E, int nb) {
    __shared__ int lc[NBB];
    for (int i = threadIdx.x; i < nb; i += 256) lc[i] = 0;
    __syncthreads();
    int base = blockIdx.x * BINCHUNK;
    for (int r = 0; r < BINR; ++r) {
        int e = base + r * 256 + threadIdx.x;
        if (e < E) atomicAdd(&lc[ei[E + e] >> BSH], 1);
    }
    __syncthreads();
    for (int i = threadIdx.x; i < nb; i += 256)
        if (lc[i]) atomicAdd(&bases[i], lc[i]);
}

__global__ __launch_bounds__(SCAN_T) void scan_copy_kernel(
    int* __restrict__ data, int* __restrict__ cur, int n) {
    __shared__ int sd[SCAN_T];
    int t = threadIdx.x;
    int chunk = (n + SCAN_T - 1) / SCAN_T;
    int base = t * chunk;
    int s = 0;
    for (int i = 0; i < chunk; ++i) { int idx = base + i; if (idx < n) s += data[idx]; }
    sd[t] = s;
    __syncthreads();
    for (int off = 1; off < SCAN_T; off <<= 1) {
        int v = (t >= off) ? sd[t - off] : 0;
        __syncthreads();
        sd[t] += v;
        __syncthreads();
    }
    int run = sd[t] - s;
    for (int i = 0; i < chunk; ++i) {
        int idx = base + i;
        if (idx < n) { int v = data[idx]; data[idx] = run; cur[idx] = run; run += v; }
    }
}

// bin v3: two-pass (count, then re-read + place). No per-thread pl[] array ->
// low VGPR at BINR=64 -> 16K edges/block -> ~84-entry runs -> ~1.15x write amp.
__global__ __launch_bounds__(256) void bin_kernel(
    const int* __restrict__ ei, const float* __restrict__ ew,
    int* __restrict__ cur, unsigned int* __restrict__ binned,
    __half* __restrict__ bw, int E, int nb) {
    __shared__ int lcnt[NBB];
    __shared__ int lbase[NBB];
    __shared__ int lcur[NBB];
    for (int i = threadIdx.x; i < nb; i += 256) lcnt[i] = 0;
    __syncthreads();
    int base = blockIdx.x * BINCHUNK;
    for (int r = 0; r < BINR; ++r) {
        int e = base + r * 256 + threadIdx.x;
        if (e < E) atomicAdd(&lcnt[ei[E + e] >> BSH], 1);
    }
    __syncthreads();
    for (int i = threadIdx.x; i < nb; i += 256) {
        if (lcnt[i]) lbase[i] = atomicAdd(&cur[i], lcnt[i]);
        lcur[i] = 0;
    }
    __syncthreads();
    for (int r = 0; r < BINR; ++r) {
        int e = base + r * 256 + threadIdx.x;
        if (e < E) {
            int d = ei[E + e];
            int b = d >> BSH;
            int pos = lbase[b] + atomicAdd(&lcur[b], 1);
            binned[pos] = (unsigned int)ei[e] | ((unsigned int)(d & (BSZ - 1)) << 17);
            bw[pos] = __float2half(ew[e]);
        }
    }
}

// one block per 512-node bucket: LDS hist + scan; csr window 128KB, L2-resident
__global__ __launch_bounds__(512) void build_kernel(
    const int* __restrict__ bases, const int* __restrict__ cur,
    const unsigned int* __restrict__ binned, const __half* __restrict__ bw,
    int* __restrict__ rowptr, int2* __restrict__ csr, int n) {
    __shared__ int h[BSZ], s[BSZ], bump[BSZ];
    int b = blockIdx.x;
    int t = threadIdx.x;
    int base = bases[b], end = cur[b];
    int cntb = end - base;
    h[t] = 0; bump[t] = 0;
    __syncthreads();
    for (int i = t; i < cntb; i += 512)
        atomicAdd(&h[binned[base + i] >> 17], 1);
    __syncthreads();
    s[t] = h[t];
    __syncthreads();
    for (int off = 1; off < BSZ; off <<= 1) {
        int v = (t >= off) ? s[t - off] : 0;
        __syncthreads();
        s[t] += v;
        __syncthreads();
    }
    int d = b * BSZ + t;
    if (d < n) rowptr[d] = base + s[t];
    __syncthreads();
    for (int i = t; i < cntb; i += 512) {
        unsigned int v = binned[base + i];
        int dl = v >> 17;
        int src = v & 0x1FFFF;
        int p = atomicAdd(&bump[dl], 1);
        int pos = base + (s[dl] - h[dl]) + p;
        csr[pos] = make_int2(src, __float_as_int(__half2float(bw[base + i])));
    }
}

// --- Layer 1: deg from CSR, dinv, y = dinv*(x@W1) (split fp16 out) ----------
// y split 16+5: ya[n][16] (32B rows, 3.2MB) + yb[n][8] (16B rows, 1.6MB)
// -> 4.8MB total fits (mostly) in the 4MB per-XCD L2 vs 6.4MB before.
__global__ __launch_bounds__(256) void node_l1_kernel(
    const float* __restrict__ x, const int* __restrict__ rowptr,
    const int2* __restrict__ csr, const float* __restrict__ W,
    float* __restrict__ dinv, __half* __restrict__ ya, __half* __restrict__ yb,
    int n) {
    __shared__ float Ws[NF * NF];
    for (int i = threadIdx.x; i < NF * NF; i += 256) Ws[i] = W[i];
    __syncthreads();
    int i = blockIdx.x * 256 + threadIdx.x;
    if (i >= n) return;
    int start = (i == 0) ? 0 : rowptr[i - 1], end = rowptr[i];
    float deg = 0.f;
    int e = start;
    for (; e + 3 < end; e += 4) {
        int2 c0 = csr[e], c1 = csr[e + 1], c2 = csr[e + 2], c3 = csr[e + 3];
        deg += __int_as_float(c0.y) + __int_as_float(c1.y)
             + __int_as_float(c2.y) + __int_as_float(c3.y);
    }
    for (; e < end; ++e) deg += __int_as_float(csr[e].y);
    float di = rsqrtf(deg + 1.0f);
    dinv[i] = di;
    float xr[NF];
    #pragma unroll
    for (int f = 0; f < NF; ++f) xr[f] = x[i * NF + f];
    #pragma unroll
    for (int j = 0; j < NF; ++j) {
        float v = 0.f;
        #pragma unroll
        for (int f = 0; f < NF; ++f) v += xr[f] * Ws[f * NF + j];
        float yv = di * v;
        if (j < 16) ya[(size_t)i * 16 + j] = __float2half(yv);
        else        yb[(size_t)i * 8 + (j - 16)] = __float2half(yv);
    }
}

// r10's gather (best measured): unroll x8 for MLP, scalar tail.
// yp/stride/off select the feature plane (static per lane).
static __device__ __forceinline__ float gather_seg(
    const int2* __restrict__ csr, const __half* __restrict__ yp,
    int stride, int off, int start, int end) {
    float g = 0.f;
    int e = start;
    for (; e + 7 < end; e += 8) {
        int2 c0 = csr[e + 0], c1 = csr[e + 1], c2 = csr[e + 2], c3 = csr[e + 3];
        int2 c4 = csr[e + 4], c5 = csr[e + 5], c6 = csr[e + 6], c7 = csr[e + 7];
        float a0 = __half2float(yp[(size_t)c0.x * stride + off]);
        float a1 = __half2float(yp[(size_t)c1.x * stride + off]);
        float a2 = __half2float(yp[(size_t)c2.x * stride + off]);
        float a3 = __half2float(yp[(size_t)c3.x * stride + off]);
        float a4 = __half2float(yp[(size_t)c4.x * stride + off]);
        float a5 = __half2float(yp[(size_t)c5.x * stride + off]);
        float a6 = __half2float(yp[(size_t)c6.x * stride + off]);
        float a7 = __half2float(yp[(size_t)c7.x * stride + off]);
        g += __int_as_float(c0.y) * a0 + __int_as_float(c1.y) * a1
           + __int_as_float(c2.y) * a2 + __int_as_float(c3.y) * a3
           + __int_as_float(c4.y) * a4 + __int_as_float(c5.y) * a5
           + __int_as_float(c6.y) * a6 + __int_as_float(c7.y) * a7;
    }
    for (; e < end; ++e) {
        int2 c = csr[e];
        g += __int_as_float(c.y) * __half2float(yp[(size_t)c.x * stride + off]);
    }
    return g;
}

// --- Fused GCN layer (layers 2,3): gather + prev finish + matvec ------------
__global__ __launch_bounds__(256) void layer_kernel(
    const int* __restrict__ rowptr, const int2* __restrict__ csr,
    const float* __restrict__ dinv, const float* __restrict__ bprev,
    const float* __restrict__ W,
    const __half* __restrict__ yina, const __half* __restrict__ yinb,
    __half* __restrict__ youta, __half* __restrict__ youtb, int n) {
    __shared__ float Ws[NF * NF];
    __shared__ float bsh[NF];
    __shared__ float xr[BN][NF];
    for (int i = threadIdx.x; i < NF * NF; i += 256) Ws[i] = W[i];
    if (threadIdx.x < NF) bsh[threadIdx.x] = bprev[threadIdx.x];
    __syncthreads();
    int t = threadIdx.x;
    int nd = t / NF, f = t - nd * NF;
    int d = blockIdx.x * BN + nd;
    bool act = (nd < BN) && (d < n);
    const __half* yp = (f < 16) ? yina : yinb;
    int stride = (f < 16) ? 16 : 8;
    int off = (f < 16) ? f : f - 16;
    float di = 0.f;
    if (act) {
        di = dinv[d];
        int start = (d == 0) ? 0 : rowptr[d - 1], end = rowptr[d];
        float g = gather_seg(csr, yp, stride, off, start, end);
        xr[nd][f] = di * (g + __half2float(yp[(size_t)d * stride + off])) + bsh[f];
    }
    __syncthreads();
    if (act) {
        float v = 0.f;
        #pragma unroll
        for (int k = 0; k < NF; ++k) v += xr[nd][k] * Ws[k * NF + f];
        float yv = di * v;
        if (f < 16) youta[(size_t)d * 16 + f] = __float2half(yv);
        else        youtb[(size_t)d * 8 + off] = __float2half(yv);
    }
}

// --- Final fused: gather + relu + block-level mean-pool partials ------------
__global__ __launch_bounds__(256) void final_pool_kernel(
    const int* __restrict__ rowptr, const int2* __restrict__ csr,
    const float* __restrict__ dinv, const float* __restrict__ b3,
    const int* __restrict__ batch,
    const __half* __restrict__ yina, const __half* __restrict__ yinb,
    float* __restrict__ sums, float* __restrict__ cnt, int n) {
    __shared__ float bsh[NF];
    __shared__ float xr[BN][NF];
    __shared__ int gs[BN];
    if (threadIdx.x < NF) bsh[threadIdx.x] = b3[threadIdx.x];
    __syncthreads();
    int t = threadIdx.x;
    int nd = t / NF, f = t - nd * NF;
    int base = blockIdx.x * BN;
    int nvalid = n - base; if (nvalid > BN) nvalid = BN;
    int d = base + nd;
    bool act = (nd < BN) && (d < n);
    const __half* yp = (f < 16) ? yina : yinb;
    int stride = (f < 16) ? 16 : 8;
    int off = (f < 16) ? f : f - 16;
    if (act) {
        int start = (d == 0) ? 0 : rowptr[d - 1], end = rowptr[d];
        float g = gather_seg(csr, yp, stride, off, start, end);
        float h = dinv[d] * (g + __half2float(yp[(size_t)d * stride + off])) + bsh[f];
        xr[nd][f] = fmaxf(h, 0.f);
        if (f == 0) gs[nd] = batch[d];
    }
    __syncthreads();
    if (nvalid <= 0) return;
    if (t < NF) {           // per-feature: run-length pooled atomics (batch sorted)
        float run = 0.f;
        int gcur = gs[0];
        for (int k = 0; k < nvalid; ++k) {
            int g = gs[k];
            if (g != gcur) { ATOMIC_ADD_F32(&sums[gcur * NF + t], run); run = 0.f; gcur = g; }
            run += xr[k][t];
        }
        ATOMIC_ADD_F32(&sums[gcur * NF + t], run);
    } else if (t == NF) {
        float run = 0.f;
        int gcur = gs[0];
        for (int k = 0; k < nvalid; ++k) {
            int g = gs[k];
            if (g != gcur) { ATOMIC_ADD_F32(&cnt[gcur], run); run = 0.f; gcur = g; }
            run += 1.f;
        }
        ATOMIC_ADD_F32(&cnt[gcur], run);
    }
}

// --- MLP + softmax: one block per graph; fp32 output -------------------------
__global__ __launch_bounds__(256) void mlp_kernel(
    const float* __restrict__ sums, const float* __restrict__ cnt,
    const float* __restrict__ Wp,  const float* __restrict__ bp,
    const float* __restrict__ Wf1, const float* __restrict__ bf1,
    const float* __restrict__ Wf2, const float* __restrict__ bf2,
    const float* __restrict__ Wo,  const float* __restrict__ bo,
    float* __restrict__ out) {
    int g = blockIdx.x;
    int t = threadIdx.x;
    __shared__ float xr[NF], h1[128], h2[256], h3[64];
    if (t < NF) xr[t] = sums[g * NF + t] / fmaxf(cnt[g], 1.0f);
    __syncthreads();
    if (t < 128) {
        float v = bp[t];
        #pragma unroll
        for (int f = 0; f < NF; ++f) v += xr[f] * Wp[f * 128 + t];
        h1[t] = v >= 0.f ? v : 0.01f * v;
    }
    __syncthreads();
    {
        float v = bf1[t];
        for (int k = 0; k < 128; ++k) v += h1[k] * Wf1[k * 256 + t];
        h2[t] = v >= 0.f ? v : 0.01f * v;
    }
    __syncthreads();
    if (t < 64) {
        float v = bf2[t];
        for (int k = 0; k < 256; ++k) v += h2[k] * Wf2[k * 64 + t];
        h3[t] = v >= 0.f ? v : 0.01f * v;
    }
    __syncthreads();
    if (t == 0) {
        float lg[5];
        float m = -1e30f;
        for (int j = 0; j < 5; ++j) {
            float v = bo[j];
            for (int k = 0; k < 64; ++k) v += h3[k] * Wo[k * 5 + j];
            lg[j] = v;
            m = fmaxf(m, v);
        }
        float den = 0.f;
        for (int j = 0; j < 5; ++j) { lg[j] = __expf(lg[j] - m); den += lg[j]; }
        for (int j = 0; j < 5; ++j) out[g * 5 + j] = lg[j] / den;
    }
}

extern "C" void kernel_launch(void* const* d_in, const int* in_sizes, int n_in,
                              void* d_out, int out_size, void* d_ws, size_t ws_size,
                              hipStream_t stream) {
    const float* x     = (const float*)d_in[0];
    const int*   ei    = (const int*)d_in[1];
    const float* ew    = (const float*)d_in[2];
    const int*   batch = (const int*)d_in[3];
    const float* W1 = (const float*)d_in[4];
    const float* b1 = (const float*)d_in[5];
    const float* W2 = (const float*)d_in[6];
    const float* b2 = (const float*)d_in[7];
    const float* W3 = (const float*)d_in[8];
    const float* b3 = (const float*)d_in[9];
    const float* Wp  = (const float*)d_in[10];
    const float* bp  = (const float*)d_in[11];
    const float* Wf1 = (const float*)d_in[12];
    const float* bf1 = (const float*)d_in[13];
    const float* Wf2 = (const float*)d_in[14];
    const float* bf2 = (const float*)d_in[15];
    const float* Wo  = (const float*)d_in[16];
    const float* bo  = (const float*)d_in[17];

    const int n = in_sizes[0] / NF;   // 100000
    const int E = in_sizes[2];        // 3200000
    const int B = out_size / 5;       // 64
    const int nb = (n + BSZ - 1) >> BSH;  // 196 buckets

    // y region: 2 buffers x (n*16 + n*8) halves = n*24 words; binned overlay needs E words
    const size_t y_words = ((size_t)n * 24 > (size_t)E) ? (size_t)n * 24 : (size_t)E;
    const size_t need_words = (size_t)2 * E + 2 * (size_t)n + y_words
                            + (size_t)B * NF + B + ((size_t)E + 1) / 2 + 2 * NBMAX;
    if (ws_size < need_words * 4 || nb > NBB) {
        sentinel_kernel<<<(out_size + 63) / 64, 64, 0, stream>>>((float*)d_out, out_size);
        return;
    }

    int*   wsw    = (int*)d_ws;
    int2*  csr    = (int2*)wsw;
    int*   rowptr = wsw + (size_t)2 * E;
    float* dinv   = (float*)(wsw + (size_t)2 * E + n);
    int*   yreg   = wsw + (size_t)2 * E + 2 * (size_t)n;   // 32B-aligned (2E+2n % 8 == 0)
    __half* yAa   = (__half*)yreg;                 // n*16 halves (32B rows)
    __half* yAb   = yAa + (size_t)n * 16;          // n*8  halves (16B rows)
    __half* yBa   = yAb + (size_t)n * 8;           // n*16
    __half* yBb   = yBa + (size_t)n * 16;          // n*8
    unsigned int* binned = (unsigned int*)yreg;    // overlay (dead before y buffers live)
    float* sums   = (float*)(yreg + y_words);
    float* cnt    = sums + (size_t)B * NF;
    __half* bw    = (__half*)(cnt + B);
    int*   bases  = (int*)(bw + 2 * (((size_t)E + 1) / 2));
    int*   cur    = bases + NBMAX;

    hipMemsetAsync(bases, 0, (size_t)nb * sizeof(int), stream);
    hipMemsetAsync(sums, 0, (size_t)(B * NF + B) * sizeof(float), stream);

    int nb_bin = (E + BINCHUNK - 1) / BINCHUNK;   // 196 blocks
    int nb_n   = (n + 255) / 256;
    int nb_g   = (n + BN - 1) / BN;

    bucket_count_kernel<<<nb_bin, 256, 0, stream>>>(ei, bases, E, nb);
    scan_copy_kernel<<<1, SCAN_T, 0, stream>>>(bases, cur, nb);
    bin_kernel<<<nb_bin, 256, 0, stream>>>(ei, ew, cur, binned, bw, E, nb);
    build_kernel<<<nb, 512, 0, stream>>>(bases, cur, binned, bw, rowptr, csr, n);

    node_l1_kernel<<<nb_n, 256, 0, stream>>>(x, rowptr, csr, W1, dinv, yAa, yAb, n);
    layer_kernel<<<nb_g, 256, 0, stream>>>(rowptr, csr, dinv, b1, W2,
                                           yAa, yAb, yBa, yBb, n);
    layer_kernel<<<nb_g, 256, 0, stream>>>(rowptr, csr, dinv, b2, W3,
                                           yBa, yBb, yAa, yAb, n);
    final_pool_kernel<<<nb_g, 256, 0, stream>>>(rowptr, csr, dinv, b3, batch,
                                                yAa, yAb, sums, cnt, n);
    mlp_kernel<<<B, 256, 0, stream>>>(sums, cnt, Wp, bp, Wf1, bf1, Wf2, bf2, Wo, bo,
                                      (float*)d_out);
}